// Round 1
// baseline (112.286 us; speedup 1.0000x reference)
//
#include <hip/hip_runtime.h>

static constexpr int   KBINS = 16;
static constexpr float TB    = 3.0f;
static constexpr float MIN_W = 0.001f;
static constexpr float MIN_H = 0.001f;
static constexpr float MIN_D = 0.001f;
static constexpr int   PPL   = 47;    // params per layer (3*16-1)
static constexpr int   PPE   = 188;   // params per element (4 layers)

__device__ __forceinline__ float softplusf(float v) {
  // stable: max(v,0) + log(1 + exp(-|v|))  == jax.nn.softplus
  return fmaxf(v, 0.0f) + __logf(1.0f + __expf(-fabsf(v)));
}

// Load N consecutive floats starting at compile-time float offset O within the
// element's 188-float (16B-aligned) param record, using aligned float4 loads.
// All indices are compile-time after unrolling -> pure register extraction.
template<int O, int N>
__device__ __forceinline__ void loadN(const float4* __restrict__ p4, float* a) {
  constexpr int C0 = O >> 2;
  constexpr int C1 = (O + N - 1) >> 2;
  constexpr int NC = C1 - C0 + 1;
  float4 ch[NC];
#pragma unroll
  for (int j = 0; j < NC; ++j) ch[j] = p4[C0 + j];
#pragma unroll
  for (int k = 0; k < N; ++k) {
    const int f = O + k - (C0 << 2);
    const int j = f >> 2, c = f & 3;
    const float4 q = ch[j];
    a[k] = (c == 0) ? q.x : (c == 1) ? q.y : (c == 2) ? q.z : q.w;
  }
}

template<int LI>
__device__ __forceinline__ void rqs_layer(const float4* __restrict__ p4,
                                          float& x, float& ldsum) {
  constexpr int O = LI * PPL;
  const float xc = fminf(fmaxf(x, -TB), TB);

  // ---- widths: softmax -> bin edges, select containing bin ----
  float uw[KBINS];
  loadN<O, KBINS>(p4, uw);
  float m = uw[0];
#pragma unroll
  for (int k = 1; k < KBINS; ++k) m = fmaxf(m, uw[k]);
  float s = 0.0f;
#pragma unroll
  for (int k = 0; k < KBINS; ++k) { uw[k] = __expf(uw[k] - m); s += uw[k]; }
  const float csw = (1.0f - KBINS * MIN_W) / s;

  float cum = 0.0f, ek = -TB;
  float xk = -TB, xk1 = TB;
  int idx = 0;
#pragma unroll
  for (int k = 0; k < KBINS; ++k) {
    cum += fmaf(uw[k], csw, MIN_W);
    const float ek1 = (k == KBINS - 1) ? TB : fmaf(2.0f * TB, cum, -TB);
    if (xc >= ek) { idx = k; xk = ek; xk1 = ek1; }  // last k with xc >= edge[k]
    ek = ek1;
  }
  const float wk = xk1 - xk;

  // ---- heights: softmax -> y edges, gather at idx ----
  float uh[KBINS];
  loadN<O + KBINS, KBINS>(p4, uh);
  m = uh[0];
#pragma unroll
  for (int k = 1; k < KBINS; ++k) m = fmaxf(m, uh[k]);
  s = 0.0f;
#pragma unroll
  for (int k = 0; k < KBINS; ++k) { uh[k] = __expf(uh[k] - m); s += uh[k]; }
  const float csh = (1.0f - KBINS * MIN_H) / s;

  cum = 0.0f; ek = -TB;
  float yk = -TB, yk1 = TB;
#pragma unroll
  for (int k = 0; k < KBINS; ++k) {
    cum += fmaf(uh[k], csh, MIN_H);
    const float ek1 = (k == KBINS - 1) ? TB : fmaf(2.0f * TB, cum, -TB);
    if (k == idx) { yk = ek; yk1 = ek1; }
    ek = ek1;
  }
  const float hk = yk1 - yk;

  // ---- derivatives: pad gives derivs[0]=derivs[16]=1.0; compute only the 2 needed ----
  float ud[KBINS - 1];
  loadN<O + 2 * KBINS, KBINS - 1>(p4, ud);
  float udk = 0.0f, udk1 = 0.0f;
#pragma unroll
  for (int j = 0; j < KBINS - 1; ++j) {
    if (j == idx - 1) udk  = ud[j];
    if (j == idx)     udk1 = ud[j];
  }
  const float dk  = (idx == 0)         ? 1.0f : MIN_D + softplusf(udk);
  const float dk1 = (idx == KBINS - 1) ? 1.0f : MIN_D + softplusf(udk1);

  // ---- rational-quadratic spline (forward) ----
  const float delta = hk / wk;
  const float theta = (xc - xk) / wk;
  const float omt   = 1.0f - theta;
  const float t1m   = theta * omt;
  const float denom = delta + (dk + dk1 - 2.0f * delta) * t1m;
  const float y     = yk + hk * (delta * theta * theta + dk * t1m) / denom;
  const float dnum  = (delta * delta) *
                      (dk1 * theta * theta + 2.0f * delta * t1m + dk * omt * omt);
  const float ld    = __logf(dnum) - 2.0f * __logf(denom);

  const bool inside = (x >= -TB) && (x <= TB);
  x      = inside ? y : x;
  ldsum += inside ? ld : 0.0f;
}

__global__ __launch_bounds__(256) void nsf_flow_kernel(
    const float* __restrict__ params, const float* __restrict__ xin,
    float* __restrict__ yout, float* __restrict__ logdet, int epb) {
  const int e = blockIdx.x * 256 + threadIdx.x;   // grid sized exactly
  const float4* p4 = reinterpret_cast<const float4*>(params) + (size_t)e * (PPE / 4);
  float x = xin[e];
  float ldsum = 0.0f;
  rqs_layer<0>(p4, x, ldsum);
  rqs_layer<1>(p4, x, ldsum);
  rqs_layer<2>(p4, x, ldsum);
  rqs_layer<3>(p4, x, ldsum);
  yout[e] = x;

  // ---- logdet: wave reduce -> LDS -> one atomic per block ----
  float v = ldsum;
#pragma unroll
  for (int o = 32; o > 0; o >>= 1) v += __shfl_xor(v, o, 64);
  __shared__ float red[4];
  const int wid = threadIdx.x >> 6;
  if ((threadIdx.x & 63) == 0) red[wid] = v;
  __syncthreads();
  if (threadIdx.x == 0) {
    const int b = e / epb;   // whole block is within one batch (epb % 256 == 0)
    atomicAdd(&logdet[b], red[0] + red[1] + red[2] + red[3]);
  }
}

extern "C" void kernel_launch(void* const* d_in, const int* in_sizes, int n_in,
                              void* d_out, int out_size, void* d_ws, size_t ws_size,
                              hipStream_t stream) {
  const float* params = (const float*)d_in[0];
  const float* x      = (const float*)d_in[1];
  const int n   = in_sizes[1];        // 524288 elements
  const int nb  = out_size - n;       // 32 batches
  const int epb = n / nb;             // 16384 elements per batch
  float* y      = (float*)d_out;
  float* logdet = y + n;

  hipMemsetAsync(logdet, 0, nb * sizeof(float), stream);  // atomics accumulate into zeroed buf
  nsf_flow_kernel<<<dim3(n / 256), dim3(256), 0, stream>>>(params, x, y, logdet, epb);
}

// Round 2
// 111.075 us; speedup vs baseline: 1.0109x; 1.0109x over previous
//
#include <hip/hip_runtime.h>

static constexpr int   KBINS  = 16;
static constexpr float TB     = 3.0f;
static constexpr float MIN_W  = 0.001f;
static constexpr float MIN_H  = 0.001f;
static constexpr float MIN_D  = 0.001f;
static constexpr int   PPL    = 47;            // params per layer (3*16-1)
static constexpr int   REC_F4 = 47;            // float4 per record (188 floats)
static constexpr int   TILE   = 32;            // records per block (one wave)
static constexpr int   TILE_F4 = TILE * REC_F4;          // 1504
static constexpr int   NCALLS  = (TILE_F4 + 63) / 64;    // 24 staging calls

__device__ __forceinline__ float softplusf(float v) {
  return fmaxf(v, 0.0f) + __logf(1.0f + __expf(-fabsf(v)));
}

// Read N consecutive floats at compile-time float offset O within this
// thread's 47-float4 LDS record via ds_read_b128 + static extraction.
template<int O, int N>
__device__ __forceinline__ void loadN(const float4* __restrict__ p4, float* a) {
  constexpr int C0 = O >> 2;
  constexpr int C1 = (O + N - 1) >> 2;
  constexpr int NC = C1 - C0 + 1;
  float4 ch[NC];
#pragma unroll
  for (int j = 0; j < NC; ++j) ch[j] = p4[C0 + j];
#pragma unroll
  for (int k = 0; k < N; ++k) {
    const int f = O + k - (C0 << 2);
    const int j = f >> 2, c = f & 3;
    const float4 q = ch[j];
    a[k] = (c == 0) ? q.x : (c == 1) ? q.y : (c == 2) ? q.z : q.w;
  }
}

template<int LI>
__device__ __forceinline__ void rqs_layer(const float4* __restrict__ p4,
                                          float& x, float& ldsum) {
  constexpr int O = LI * PPL;
  const float xc = fminf(fmaxf(x, -TB), TB);

  // ---- widths: softmax -> bin edges, select containing bin ----
  float uw[KBINS];
  loadN<O, KBINS>(p4, uw);
  float m = uw[0];
#pragma unroll
  for (int k = 1; k < KBINS; ++k) m = fmaxf(m, uw[k]);
  float s = 0.0f;
#pragma unroll
  for (int k = 0; k < KBINS; ++k) { uw[k] = __expf(uw[k] - m); s += uw[k]; }
  const float csw = (1.0f - KBINS * MIN_W) / s;

  float cum = 0.0f, ek = -TB;
  float xk = -TB, xk1 = TB;
  int idx = 0;
#pragma unroll
  for (int k = 0; k < KBINS; ++k) {
    cum += fmaf(uw[k], csw, MIN_W);
    const float ek1 = (k == KBINS - 1) ? TB : fmaf(2.0f * TB, cum, -TB);
    if (xc >= ek) { idx = k; xk = ek; xk1 = ek1; }
    ek = ek1;
  }
  const float wk = xk1 - xk;

  // ---- heights: softmax -> y edges, gather at idx ----
  float uh[KBINS];
  loadN<O + KBINS, KBINS>(p4, uh);
  m = uh[0];
#pragma unroll
  for (int k = 1; k < KBINS; ++k) m = fmaxf(m, uh[k]);
  s = 0.0f;
#pragma unroll
  for (int k = 0; k < KBINS; ++k) { uh[k] = __expf(uh[k] - m); s += uh[k]; }
  const float csh = (1.0f - KBINS * MIN_H) / s;

  cum = 0.0f; ek = -TB;
  float yk = -TB, yk1 = TB;
#pragma unroll
  for (int k = 0; k < KBINS; ++k) {
    cum += fmaf(uh[k], csh, MIN_H);
    const float ek1 = (k == KBINS - 1) ? TB : fmaf(2.0f * TB, cum, -TB);
    if (k == idx) { yk = ek; yk1 = ek1; }
    ek = ek1;
  }
  const float hk = yk1 - yk;

  // ---- derivatives: only the two needed; pad -> 1.0 at the ends ----
  float ud[KBINS - 1];
  loadN<O + 2 * KBINS, KBINS - 1>(p4, ud);
  float udk = 0.0f, udk1 = 0.0f;
#pragma unroll
  for (int j = 0; j < KBINS - 1; ++j) {
    if (j == idx - 1) udk  = ud[j];
    if (j == idx)     udk1 = ud[j];
  }
  const float dk  = (idx == 0)         ? 1.0f : MIN_D + softplusf(udk);
  const float dk1 = (idx == KBINS - 1) ? 1.0f : MIN_D + softplusf(udk1);

  // ---- rational-quadratic spline (forward) ----
  const float delta = hk / wk;
  const float theta = (xc - xk) / wk;
  const float omt   = 1.0f - theta;
  const float t1m   = theta * omt;
  const float denom = delta + (dk + dk1 - 2.0f * delta) * t1m;
  const float y     = yk + hk * (delta * theta * theta + dk * t1m) / denom;
  const float dnum  = (delta * delta) *
                      (dk1 * theta * theta + 2.0f * delta * t1m + dk * omt * omt);
  const float ld    = __logf(dnum) - 2.0f * __logf(denom);

  const bool inside = (x >= -TB) && (x <= TB);
  x      = inside ? y : x;
  ldsum += inside ? ld : 0.0f;
}

// One wave per block. Stage 32 contiguous records (48KB of a 24KB tile) into
// LDS via coalesced global_load_lds(16B), then each pair of lanes computes one
// record from LDS (lane t and t+32 broadcast-read record t&31).
__global__ __launch_bounds__(64) void nsf_flow_staged(
    const float* __restrict__ params, const float* __restrict__ xin,
    float* __restrict__ yout, float* __restrict__ partial, int n) {
  __shared__ float4 sbuf[NCALLS * 64];          // 24,576 B (incl. tail pad)
  const int T = blockIdx.x;
  const int l = threadIdx.x;

  const float4* gp = reinterpret_cast<const float4*>(params);
  const long nf4 = (long)n * REC_F4;
  const long f40 = (long)T * TILE_F4 + l;
#pragma unroll
  for (int i = 0; i < NCALLS; ++i) {
    long idx = f40 + (long)i * 64;
    idx = (idx < nf4) ? idx : (nf4 - 1);        // clamp: last call of last tile
    __builtin_amdgcn_global_load_lds(
        (const __attribute__((address_space(1))) void*)(gp + idx),
        (__attribute__((address_space(3))) void*)(&sbuf[i * 64]),
        16, 0, 0);
  }

  const int r = l & (TILE - 1);
  const int e = T * TILE + r;
  float x = xin[e];

  asm volatile("s_waitcnt vmcnt(0)" ::: "memory");
  __builtin_amdgcn_s_barrier();

  const float4* rec4 = &sbuf[r * REC_F4];
  float ldsum = 0.0f;
  rqs_layer<0>(rec4, x, ldsum);
  rqs_layer<1>(rec4, x, ldsum);
  rqs_layer<2>(rec4, x, ldsum);
  rqs_layer<3>(rec4, x, ldsum);

  if (l < TILE) yout[e] = x;

  float v = (l < TILE) ? ldsum : 0.0f;
#pragma unroll
  for (int o = 32; o > 0; o >>= 1) v += __shfl_xor(v, o, 64);
  if (l == 0) atomicAdd(&partial[T >> 3], v);   // 8 tiles/slot -> low contention
}

// Sum the per-slot partials into logdet[b]; slots are batch-contiguous.
__global__ __launch_bounds__(64) void nsf_reduce(
    const float* __restrict__ partial, float* __restrict__ logdet, int spb) {
  const int b = blockIdx.x, l = threadIdx.x;
  float v = 0.0f;
  for (int s = l; s < spb; s += 64) v += partial[b * spb + s];
#pragma unroll
  for (int o = 32; o > 0; o >>= 1) v += __shfl_xor(v, o, 64);
  if (l == 0) logdet[b] = v;
}

extern "C" void kernel_launch(void* const* d_in, const int* in_sizes, int n_in,
                              void* d_out, int out_size, void* d_ws, size_t ws_size,
                              hipStream_t stream) {
  const float* params = (const float*)d_in[0];
  const float* x      = (const float*)d_in[1];
  const int n     = in_sizes[1];       // 524288 elements
  const int nb    = out_size - n;      // 32 batches
  const int tiles = n / TILE;          // 16384
  const int slots = tiles / 8;         // 2048 partial slots
  const int spb   = slots / nb;        // 64 slots per batch
  float* y      = (float*)d_out;
  float* logdet = y + n;
  float* partial = (float*)d_ws;

  hipMemsetAsync(partial, 0, slots * sizeof(float), stream);
  nsf_flow_staged<<<dim3(tiles), dim3(64), 0, stream>>>(params, x, y, partial, n);
  nsf_reduce<<<dim3(nb), dim3(64), 0, stream>>>(partial, logdet, spb);
}

// Round 3
// 96.167 us; speedup vs baseline: 1.1676x; 1.1550x over previous
//
#include <hip/hip_runtime.h>

static constexpr int   KBINS = 16;
static constexpr float TB    = 3.0f;
static constexpr float MIN_W = 0.001f;
static constexpr float MIN_H = 0.001f;
static constexpr float MIN_D = 0.001f;
static constexpr int   PPL   = 47;    // params per layer (3*16-1)

__device__ __forceinline__ float softplusf(float v) {
  return fmaxf(v, 0.0f) + __logf(1.0f + __expf(-fabsf(v)));
}

// Compile-time chunk window covering layer LI's 47 floats within the
// 47-float4 (16B-aligned) element record.
template<int LI> struct CR {
  static constexpr int C0 = (LI * PPL) / 4;
  static constexpr int C1 = (LI * PPL + PPL - 1) / 4;
  static constexpr int NC = C1 - C0 + 1;           // 12 or 13
};

template<int LI>
__device__ __forceinline__ void loadLayer(const float4* __restrict__ p4, float4* ch) {
#pragma unroll
  for (int j = 0; j < CR<LI>::NC; ++j) ch[j] = p4[CR<LI>::C0 + j];
}

// Extract N floats at layer-offset O from the chunk buffer; all indices are
// compile-time after unrolling -> pure register selects, no scratch.
template<int LI, int O, int N>
__device__ __forceinline__ void extractN(const float4* ch, float* a) {
  constexpr int BASE = LI * PPL + O - CR<LI>::C0 * 4;
#pragma unroll
  for (int k = 0; k < N; ++k) {
    const int f = BASE + k;
    const float4 q = ch[f >> 2];
    const int c = f & 3;
    a[k] = (c == 0) ? q.x : (c == 1) ? q.y : (c == 2) ? q.z : q.w;
  }
}

template<int LI>
__device__ __forceinline__ void computeLayer(const float4* ch, float& x, float& ldsum) {
  const float xc = fminf(fmaxf(x, -TB), TB);

  // ---- widths: softmax -> bin edges, select containing bin ----
  float uw[KBINS];
  extractN<LI, 0, KBINS>(ch, uw);
  float m = uw[0];
#pragma unroll
  for (int k = 1; k < KBINS; ++k) m = fmaxf(m, uw[k]);
  float s = 0.0f;
#pragma unroll
  for (int k = 0; k < KBINS; ++k) { uw[k] = __expf(uw[k] - m); s += uw[k]; }
  const float csw = (1.0f - KBINS * MIN_W) / s;

  float cum = 0.0f, ek = -TB;
  float xk = -TB, xk1 = TB;
  int idx = 0;
#pragma unroll
  for (int k = 0; k < KBINS; ++k) {
    cum += fmaf(uw[k], csw, MIN_W);
    const float ek1 = (k == KBINS - 1) ? TB : fmaf(2.0f * TB, cum, -TB);
    if (xc >= ek) { idx = k; xk = ek; xk1 = ek1; }
    ek = ek1;
  }
  const float wk = xk1 - xk;

  // ---- heights: softmax -> y edges, gather at idx ----
  float uh[KBINS];
  extractN<LI, KBINS, KBINS>(ch, uh);
  m = uh[0];
#pragma unroll
  for (int k = 1; k < KBINS; ++k) m = fmaxf(m, uh[k]);
  s = 0.0f;
#pragma unroll
  for (int k = 0; k < KBINS; ++k) { uh[k] = __expf(uh[k] - m); s += uh[k]; }
  const float csh = (1.0f - KBINS * MIN_H) / s;

  cum = 0.0f; ek = -TB;
  float yk = -TB, yk1 = TB;
#pragma unroll
  for (int k = 0; k < KBINS; ++k) {
    cum += fmaf(uh[k], csh, MIN_H);
    const float ek1 = (k == KBINS - 1) ? TB : fmaf(2.0f * TB, cum, -TB);
    if (k == idx) { yk = ek; yk1 = ek1; }
    ek = ek1;
  }
  const float hk = yk1 - yk;

  // ---- derivatives: only the two needed; pad -> 1.0 at the ends ----
  float ud[KBINS - 1];
  extractN<LI, 2 * KBINS, KBINS - 1>(ch, ud);
  float udk = 0.0f, udk1 = 0.0f;
#pragma unroll
  for (int j = 0; j < KBINS - 1; ++j) {
    if (j == idx - 1) udk  = ud[j];
    if (j == idx)     udk1 = ud[j];
  }
  const float dk  = (idx == 0)         ? 1.0f : MIN_D + softplusf(udk);
  const float dk1 = (idx == KBINS - 1) ? 1.0f : MIN_D + softplusf(udk1);

  // ---- rational-quadratic spline (forward) ----
  const float rw    = 1.0f / wk;
  const float delta = hk * rw;
  const float theta = (xc - xk) * rw;
  const float omt   = 1.0f - theta;
  const float t1m   = theta * omt;
  const float denom = delta + (dk + dk1 - 2.0f * delta) * t1m;
  const float y     = yk + hk * (delta * theta * theta + dk * t1m) / denom;
  const float dnum  = (delta * delta) *
                      (dk1 * theta * theta + 2.0f * delta * t1m + dk * omt * omt);
  const float ld    = __logf(dnum) - 2.0f * __logf(denom);

  const bool inside = (x >= -TB) && (x <= TB);
  x      = inside ? y : x;
  ldsum += inside ? ld : 0.0f;
}

// One element per thread; register double-buffer prefetches layer L+1's
// param chunks while layer L computes (counted vmcnt keeps them in flight).
// __launch_bounds__(256,3) caps VGPR (~170) -> 12 waves/CU for TLP cover.
__global__ __launch_bounds__(256, 3) void nsf_flow_pf(
    const float* __restrict__ params, const float* __restrict__ xin,
    float* __restrict__ yout, float* __restrict__ logdet, int epb) {
  const int e = blockIdx.x * 256 + threadIdx.x;   // grid sized exactly
  const float4* p4 = reinterpret_cast<const float4*>(params) + (size_t)e * PPL;

  float4 bufA[13], bufB[13];
  loadLayer<0>(p4, bufA);
  float x = xin[e];
  float ldsum = 0.0f;

  loadLayer<1>(p4, bufB);      // prefetch L1
  computeLayer<0>(bufA, x, ldsum);
  loadLayer<2>(p4, bufA);      // prefetch L2
  computeLayer<1>(bufB, x, ldsum);
  loadLayer<3>(p4, bufB);      // prefetch L3
  computeLayer<2>(bufA, x, ldsum);
  computeLayer<3>(bufB, x, ldsum);

  yout[e] = x;

  // ---- logdet: wave reduce -> LDS -> one atomic per block ----
  float v = ldsum;
#pragma unroll
  for (int o = 32; o > 0; o >>= 1) v += __shfl_xor(v, o, 64);
  __shared__ float red[4];
  const int wid = threadIdx.x >> 6;
  if ((threadIdx.x & 63) == 0) red[wid] = v;
  __syncthreads();
  if (threadIdx.x == 0) {
    const int b = e / epb;     // whole block lies in one batch (epb % 256 == 0)
    atomicAdd(&logdet[b], red[0] + red[1] + red[2] + red[3]);
  }
}

extern "C" void kernel_launch(void* const* d_in, const int* in_sizes, int n_in,
                              void* d_out, int out_size, void* d_ws, size_t ws_size,
                              hipStream_t stream) {
  const float* params = (const float*)d_in[0];
  const float* x      = (const float*)d_in[1];
  const int n   = in_sizes[1];        // 524288 elements
  const int nb  = out_size - n;       // 32 batches
  const int epb = n / nb;             // 16384 elements per batch
  float* y      = (float*)d_out;
  float* logdet = y + n;

  hipMemsetAsync(logdet, 0, nb * sizeof(float), stream);
  nsf_flow_pf<<<dim3(n / 256), dim3(256), 0, stream>>>(params, x, y, logdet, epb);
}